// Round 8
// baseline (245.538 us; speedup 1.0000x reference)
//
#include <hip/hip_runtime.h>
#include <math.h>

#define T_OBS 256
#define NY 128
#define NITER 150

typedef float f2 __attribute__((ext_vector_type(2)));

// ---- gfx9/CDNA DPP wave64 reduction: row_shr 1,2,4,8 + bcast15 + bcast31 ----
#define DPP_ROW_SHR1 0x111
#define DPP_ROW_SHR2 0x112
#define DPP_ROW_SHR4 0x114
#define DPP_ROW_SHR8 0x118
#define DPP_BCAST15  0x142
#define DPP_BCAST31  0x143

#define DPP_ADD_F32(x, ctrl) \
    (x) += __int_as_float(__builtin_amdgcn_update_dpp(0, __float_as_int(x), (ctrl), 0xf, 0xf, true))

// Interleaved dual wave-sum; returns uniform totals in a,b.
__device__ __forceinline__ void wave_sum2(float& a, float& b) {
    DPP_ADD_F32(a, DPP_ROW_SHR1); DPP_ADD_F32(b, DPP_ROW_SHR1);
    DPP_ADD_F32(a, DPP_ROW_SHR2); DPP_ADD_F32(b, DPP_ROW_SHR2);
    DPP_ADD_F32(a, DPP_ROW_SHR4); DPP_ADD_F32(b, DPP_ROW_SHR4);
    DPP_ADD_F32(a, DPP_ROW_SHR8); DPP_ADD_F32(b, DPP_ROW_SHR8);
    DPP_ADD_F32(a, DPP_BCAST15);  DPP_ADD_F32(b, DPP_BCAST15);
    DPP_ADD_F32(a, DPP_BCAST31);  DPP_ADD_F32(b, DPP_BCAST31);
    a = __int_as_float(__builtin_amdgcn_readlane(__float_as_int(a), 63));
    b = __int_as_float(__builtin_amdgcn_readlane(__float_as_int(b), 63));
}

__device__ __forceinline__ float rl(float x, int l) {
    return __int_as_float(__builtin_amdgcn_readlane(__float_as_int(x), l));
}

// Pack two wave-uniform floats (SGPR-resident readlane results) into a 64-bit
// scalar -> adjacent SGPR pair; packing is SALU-only (parallel scalar pipe).
__device__ __forceinline__ unsigned long long pk2(float lo, float hi) {
    return ((unsigned long long)(unsigned int)__float_as_int(hi) << 32) |
           (unsigned int)__float_as_int(lo);
}

// Packed fp32 FMA with scalar-pair broadcast: acc.lo += s.lo*v.lo; acc.hi += s.hi*v.hi
__device__ __forceinline__ void pk_fma_s(f2& acc, unsigned long long spair, f2 v) {
    asm("v_pk_fma_f32 %0, %1, %2, %0" : "+v"(acc) : "s"(spair), "v"(v));
}

// ---------------- kernel 1: Y_hat = X @ W^T + b ; ep = Y - Y_hat ----------------
__global__ __launch_bounds__(128)
void pred_kernel(const float* __restrict__ X, const float* __restrict__ Y,
                 const float* __restrict__ W, const float* __restrict__ b,
                 float* __restrict__ yhat, float* __restrict__ ep) {
    __shared__ float xrow[64];
    const int t = blockIdx.x;
    const int j = threadIdx.x;
    if (j < 64) xrow[j] = X[t * 64 + j];
    __syncthreads();
    const float* wr = W + j * 64;
    float acc = 0.f;
#pragma unroll
    for (int x = 0; x < 64; ++x) acc = fmaf(xrow[x], wr[x], acc);
    const float yh = acc + b[j];
    yhat[t * NY + j] = yh;
    ep[t * NY + j] = Y[t * NY + j] - yh;
}

// ---------------- kernel 2: one DRO solve per block ----------------
// R7 structure (ONE barrier/iter, ungated-threshold projection), with phases
// A/B issued as v_pk_fma_f32 (2 FMA/instr). Broadcast values stay on the
// scalar file: readlane pairs packed into SGPR pairs feed VOP3P's scalar
// operand — no LDS pipe involvement (R3's failure mode). All partial-sum
// chains keep R7's exact pairing -> bit-identical output.
__global__ __launch_bounds__(256, 1)
void dro_kernel(const float* __restrict__ ep_g, const float* __restrict__ yhat_g,
                float* __restrict__ z_out,
                const float* __restrict__ d_delta, const float* __restrict__ d_gamma) {
    __shared__ float gzp[2][4][NY];              // cross-wave partials, dbuf
    __shared__ __align__(16) float red[2][8];    // cross-wave {S1,S2}, dbuf

    const int tid  = threadIdx.x;
    const int lane = tid & 63;
    const int wid  = tid >> 6;
    const int blk  = blockIdx.x;

    // row layout: thread tid holds ep[tid][0..127] as 64 adjacent f2 (128 VGPRs)
    f2 rA2[64];
    {
        const float4* eg4 = (const float4*)ep_g + tid * 32;
#pragma unroll
        for (int q = 0; q < 32; ++q) {
            const float4 t4 = eg4[q];
            f2 lo; lo.x = t4.x; lo.y = t4.y;
            f2 hi; hi.x = t4.z; hi.y = t4.w;
            rA2[2 * q] = lo; rA2[2 * q + 1] = hi;
        }
    }

    // col layout, row-paired: rBx[i] = (ep[2i][j0], ep[2i+1][j0]),
    //                         rBy[i] = (ep[2i][j0+1], ep[2i+1][j0+1])
    const int j0    = lane << 1;
    const int tbase = wid << 6;
    f2 rBx[32], rBy[32];
#pragma unroll
    for (int tt = 0; tt < 64; ++tt) {
        const float2 e = *(const float2*)(ep_g + (tbase + tt) * NY + j0);
        rBx[tt >> 1][tt & 1] = e.x;
        rBy[tt >> 1][tt & 1] = e.y;
    }

    const float yh0 = yhat_g[blk * NY + j0];
    const float yh1 = yhat_g[blk * NY + j0 + 1];

    // z pair in registers (each wave holds a full redundant copy across lanes)
    float z0 = 1.0f / 128.0f, z1 = 1.0f / 128.0f;
    // warm-start support indicators (carried across iterations)
    float act0 = 1.f, act1 = 1.f;

    const float delta = d_delta[0];
    const float gamma = d_gamma[0];
    float c = 0.f, eta = 0.f, lam = 0.1f;
    int buf = 0;

    for (int k = 0; k < NITER; ++k) {
        const float lr = 0.05f * __builtin_amdgcn_rsqf(1.0f + (float)k);

        // ---- phase A: r_t = ep[t,:].z - c ; z via SGPR-pair pk_fma ----
        f2 acc01; acc01.x = 0.f; acc01.y = 0.f;   // cols ≡0,1 (mod 4) chains
        f2 acc23; acc23.x = 0.f; acc23.y = 0.f;   // cols ≡2,3 (mod 4) chains
#pragma unroll
        for (int q = 0; q < 32; ++q) {
            const unsigned long long zp0 = pk2(rl(z0, 2 * q),     rl(z1, 2 * q));
            const unsigned long long zp1 = pk2(rl(z0, 2 * q + 1), rl(z1, 2 * q + 1));
            pk_fma_s(acc01, zp0, rA2[2 * q]);
            pk_fma_s(acc23, zp1, rA2[2 * q + 1]);
        }
        const float r  = (acc01.x + acc01.y) + (acc23.x + acc23.y) - c;
        const float q2 = r * r - eta;
        const float aa = -lam;
        const float st = (q2 > aa) ? 1.0f : ((q2 == aa) ? 0.5f : 0.0f);
        const float wv = st * r;

        // ---- S1/S2 reduction (independent of phase B; scheduler interleaves) ----
        float s1 = st, s2 = wv;
        wave_sum2(s1, s2);
        if (lane == 0) { red[buf][wid * 2] = s1; red[buf][wid * 2 + 1] = s2; }

        // ---- phase B: per-wave partial gz over own 64 rows; w via SGPR pairs ----
        f2 px; px.x = 0.f; px.y = 0.f;   // (even-row, odd-row) chains, col j0
        f2 py; py.x = 0.f; py.y = 0.f;   // (even-row, odd-row) chains, col j0+1
#pragma unroll
        for (int i = 0; i < 32; ++i) {
            const unsigned long long wp = pk2(rl(wv, 2 * i), rl(wv, 2 * i + 1));
            pk_fma_s(px, wp, rBx[i]);
            pk_fma_s(py, wp, rBy[i]);
        }
        *(float2*)&gzp[buf][wid][j0] = make_float2(px.x + px.y, py.x + py.y);

        __syncthreads();   // the ONE barrier: gzp[buf] + red[buf] visible

        // ---- all waves redundantly: scalar updates + z step + projection ----
        const float4 rd0 = *(const float4*)&red[buf][0];
        const float4 rd1 = *(const float4*)&red[buf][4];
        const float S1 = (rd0.x + rd0.z) + (rd1.x + rd1.z);
        const float S2 = (rd0.y + rd0.w) + (rd1.y + rd1.w);
        c   -= lr * (-(2.0f / 256.0f) * S2);
        eta -= lr * (1.0f - S1 * (1.0f / 256.0f));
        lam  = fmaxf(lam - lr * (delta - 1.0f + S1 * (1.0f / 256.0f)), 0.0f);

        const float2 g0v = *(const float2*)&gzp[buf][0][j0];
        const float2 g1v = *(const float2*)&gzp[buf][1][j0];
        const float2 g2v = *(const float2*)&gzp[buf][2][j0];
        const float2 g3v = *(const float2*)&gzp[buf][3][j0];
        const float g0 = (g0v.x + g1v.x) + (g2v.x + g3v.x);
        const float g1 = (g0v.y + g1v.y) + (g2v.y + g3v.y);
        const float v0 = z0 - lr * ((2.0f / 256.0f) * g0 - gamma * yh0);
        const float v1 = z1 - lr * ((2.0f / 256.0f) * g1 - gamma * yh1);

        // ---- simplex projection: ungated thresholding fixed point (R7) ----
        float theta = 0.f;
        for (int m = 0; m < 64; ++m) {
            float s  = act0 * v0 + act1 * v1;
            float cc = act0 + act1;
            wave_sum2(s, cc);
            theta = (s - 1.0f) * __builtin_amdgcn_rcpf(cc);
            const float n0 = (v0 > theta) ? 1.0f : 0.0f;
            const float n1 = (v1 > theta) ? 1.0f : 0.0f;
            const bool changed = (n0 != act0) || (n1 != act1);
            act0 = n0; act1 = n1;
            if (!__any(changed)) break;   // stable support == exact
        }
        z0 = fmaxf(v0 - theta, 0.f);
        z1 = fmaxf(v1 - theta, 0.f);

        buf ^= 1;
    }

    if (wid == 0) *(float2*)&z_out[blk * NY + j0] = make_float2(z0, z1);
}

extern "C" void kernel_launch(void* const* d_in, const int* in_sizes, int n_in,
                              void* d_out, int out_size, void* d_ws, size_t ws_size,
                              hipStream_t stream) {
    const float* X       = (const float*)d_in[0];   // 256*64
    const float* Y       = (const float*)d_in[1];   // 256*128
    const float* W       = (const float*)d_in[2];   // 128*64
    const float* b       = (const float*)d_in[3];   // 128
    const float* d_delta = (const float*)d_in[4];   // 1
    const float* d_gamma = (const float*)d_in[5];   // 1

    float* z_out    = (float*)d_out;                // Z_star: 256*128
    float* yhat_out = z_out + T_OBS * NY;           // Y_hat:  256*128
    float* ep_ws    = (float*)d_ws;                 // 256*128 scratch

    pred_kernel<<<T_OBS, 128, 0, stream>>>(X, Y, W, b, yhat_out, ep_ws);
    dro_kernel<<<T_OBS, 256, 0, stream>>>(ep_ws, yhat_out, z_out, d_delta, d_gamma);
}